// Round 4
// baseline (366.819 us; speedup 1.0000x reference)
//
#include <hip/hip_runtime.h>
#include <hip/hip_bf16.h>

#define IN_F 8192
#define OUT_F 8192
#define STATE_THRESHOLD 50.0f

typedef float f32x4 __attribute__((ext_vector_type(4)));

// One wave per output row; 512-thread blocks (8 waves = 8 rows), 1024 blocks.
// No LDS at all: the binary spike vector is bit-packed into two 64-bit
// registers per lane (exactly the 128 elements this lane gates), so the inner
// loop is pure nontemporal global float4 loads + VALU — no lgkmcnt, no
// __syncthreads, no LDS occupancy cap. 4 blocks/CU = 32 waves/CU.
__global__ __launch_bounds__(512, 8) void snn_gemv_kernel(
    const float* __restrict__ spike_input,      // [IN_F]
    const float* __restrict__ synapse_states,   // [OUT_F, IN_F]
    const float* __restrict__ membrane,         // [OUT_F]
    const float* __restrict__ adaptive_thresh,  // [OUT_F]
    const float* __restrict__ noise,            // [OUT_F]
    float* __restrict__ out)                    // [OUT_F]
{
    const int tid  = threadIdx.x;
    const int lane = tid & 63;
    const int wave = tid >> 6;

    // Prologue: pack this lane's 128 gate bits (elements 4*(lane+64*i)+j,
    // i=0..31, j=0..3) into two u64. Spike vector is 32 KiB -> L2-resident;
    // per-wave re-read is served by L2, negligible HBM traffic.
    const f32x4* sp4 = (const f32x4*)spike_input;
    unsigned long long b0 = 0ull, b1 = 0ull;
#pragma unroll
    for (int i = 0; i < 16; ++i) {
        f32x4 x = sp4[lane + 64 * i];
        unsigned long long nib =
            (unsigned long long)((x.x > 0.5f) | ((x.y > 0.5f) << 1) |
                                 ((x.z > 0.5f) << 2) | ((x.w > 0.5f) << 3));
        b0 |= nib << (4 * i);
    }
#pragma unroll
    for (int i = 0; i < 16; ++i) {
        f32x4 x = sp4[lane + 64 * (i + 16)];
        unsigned long long nib =
            (unsigned long long)((x.x > 0.5f) | ((x.y > 0.5f) << 1) |
                                 ((x.z > 0.5f) << 2) | ((x.w > 0.5f) << 3));
        b1 |= nib << (4 * i);
    }

    const int row = blockIdx.x * 8 + wave;
    const f32x4* rowp = (const f32x4*)(synapse_states + (size_t)row * IN_F);

    unsigned int cnt = 0;
    // 32 iterations of pure streaming reads: nontemporal (nt) float4 loads,
    // gate bits from registers, integer-exact accumulate.
#pragma unroll 4
    for (int i = 0; i < 16; ++i) {
        f32x4 s = __builtin_nontemporal_load(rowp + lane + 64 * i);
        unsigned int nib = (unsigned int)(b0 >> (4 * i)) & 0xFu;
        cnt += (s.x > STATE_THRESHOLD) ? (nib & 1u) : 0u;
        cnt += (s.y > STATE_THRESHOLD) ? ((nib >> 1) & 1u) : 0u;
        cnt += (s.z > STATE_THRESHOLD) ? ((nib >> 2) & 1u) : 0u;
        cnt += (s.w > STATE_THRESHOLD) ? ((nib >> 3) & 1u) : 0u;
    }
#pragma unroll 4
    for (int i = 0; i < 16; ++i) {
        f32x4 s = __builtin_nontemporal_load(rowp + lane + 64 * (i + 16));
        unsigned int nib = (unsigned int)(b1 >> (4 * i)) & 0xFu;
        cnt += (s.x > STATE_THRESHOLD) ? (nib & 1u) : 0u;
        cnt += (s.y > STATE_THRESHOLD) ? ((nib >> 1) & 1u) : 0u;
        cnt += (s.z > STATE_THRESHOLD) ? ((nib >> 2) & 1u) : 0u;
        cnt += (s.w > STATE_THRESHOLD) ? ((nib >> 3) & 1u) : 0u;
    }

    // Wave-level reduction across 64 lanes (integer, exact).
#pragma unroll
    for (int off = 32; off > 0; off >>= 1) {
        cnt += __shfl_down(cnt, off);
    }

    if (lane == 0) {
        float potential = membrane[row] + (float)cnt + noise[row];
        out[row] = (potential >= adaptive_thresh[row]) ? 1.0f : 0.0f;
    }
}

extern "C" void kernel_launch(void* const* d_in, const int* in_sizes, int n_in,
                              void* d_out, int out_size, void* d_ws, size_t ws_size,
                              hipStream_t stream) {
    const float* spike_input    = (const float*)d_in[0];
    const float* synapse_states = (const float*)d_in[1];
    const float* membrane       = (const float*)d_in[2];
    const float* adaptive_thr   = (const float*)d_in[3];
    const float* noise          = (const float*)d_in[4];
    float* out = (float*)d_out;

    dim3 grid(OUT_F / 8);   // 1024 blocks, 8 rows per block (1 per wave)
    dim3 block(512);
    snn_gemv_kernel<<<grid, block, 0, stream>>>(
        spike_input, synapse_states, membrane, adaptive_thr, noise, out);
}